// Round 4
// baseline (1951.507 us; speedup 1.0000x reference)
//
#include <hip/hip_runtime.h>

// GCN: h=relu(spmm(x@W1+b1)); out=relu(spmm(h@W2+b2))
// N=100000 nodes, E=3200000 edges, D=512.
// bf16 MFMA GEMMs; bucketed CSR-by-dst SpMM (no float atomics).
// SpMM v5: dim-sliced gather built ONLY from round-1-verified constructs.
//   Wave per (node, 64-dim slice); lane owns 1 dim (2B load, 64 lanes =
//   128B contiguous per row-slice). grid.y = 8 slices, x-major dispatch ->
//   slices run near-sequentially; hot gather table = 100k x 128B = 12.8MB
//   (L3-resident, ~31% L2-capturable per XCD) vs 102.4MB (L3-thrash).
//   deg is WAVE-UNIFORM (one node per wave); per-wave own-bucket staging.
// d_out doubles as scratch for bf16 h1/h2 (dead before final fp32 write).

#define N_NODES 100000
#define N_EDGES 3200000
#define DIM 512
#define BUCKET_CAP 128
#define NSLICE 8
#define SLICE_DIM 64

typedef __attribute__((ext_vector_type(8))) __bf16 bf16x8;
typedef __attribute__((ext_vector_type(4))) float f32x4;
typedef __attribute__((ext_vector_type(4))) unsigned int u32x4;
typedef __attribute__((ext_vector_type(2))) int i32x2;

__device__ inline unsigned short f2bf(float f) {
    unsigned int u = __builtin_bit_cast(unsigned int, f);
    unsigned int r = (u + 0x7FFFu + ((u >> 16) & 1u)) >> 16;
    return (unsigned short)r;
}
__device__ inline float bf2f(unsigned short s) {
    unsigned int u = ((unsigned int)s) << 16;
    return __builtin_bit_cast(float, u);
}

// ---- fp32 -> bf16 bulk convert (4 elems/thread) ----
__global__ __launch_bounds__(256) void k_cvt(const f32x4* __restrict__ in,
                                             ushort4* __restrict__ out, int n4) {
    int i = blockIdx.x * 256 + threadIdx.x;
    if (i >= n4) return;
    f32x4 v = __builtin_nontemporal_load(in + i);
    ushort4 o;
    o.x = f2bf(v[0]); o.y = f2bf(v[1]); o.z = f2bf(v[2]); o.w = f2bf(v[3]);
    out[i] = o;   // cached: consumed by gemm1 right after
}

// ---- W [K,N] fp32 -> Wt [N,K] bf16 (512x512) ----
__global__ __launch_bounds__(256) void k_wt(const float* __restrict__ W,
                                            unsigned short* __restrict__ Wt) {
    int idx = blockIdx.x * 256 + threadIdx.x;   // 262144 total
    int k = idx & 511, n = idx >> 9;
    Wt[n * 512 + k] = f2bf(W[k * 512 + n]);
}

// ---- edge scatter into per-dst buckets (int atomics only) ----
__global__ __launch_bounds__(256) void k_scatter(const int* __restrict__ src,
                                                 const int* __restrict__ dst,
                                                 const float* __restrict__ val,
                                                 int* __restrict__ cnt,
                                                 i32x2* __restrict__ bucket) {
    int e = blockIdx.x * 256 + threadIdx.x;
    if (e >= N_EDGES) return;
    int d = dst[e];
    int pos = atomicAdd(cnt + d, 1);
    if (pos < BUCKET_CAP) {
        i32x2 ed;
        ed[0] = src[e];
        ed[1] = __float_as_int(val[e]);
        __builtin_nontemporal_store(ed, bucket + ((size_t)d << 7) + pos);
    }
}

// ---- bf16 MFMA GEMM: C[M,512] = A[M,512] @ Bt^T + bias, C in bf16 ----
// 128x128 block tile, BK=32, 4 waves (2x2), each wave 4x4 of 16x16x32 MFMA.
__global__ __launch_bounds__(256, 2)
void k_gemm(const unsigned short* __restrict__ A, const unsigned short* __restrict__ Bt,
            const float* __restrict__ bias, unsigned short* __restrict__ C, int M) {
    __shared__ unsigned short sA[128][40];   // +8 bf16 pad: 2-way-only bank aliasing
    __shared__ unsigned short sB[128][40];
    const int t = threadIdx.x;
    const int m0 = blockIdx.y * 128;
    const int n0 = blockIdx.x * 128;
    const int wave = t >> 6;
    const int lane = t & 63;
    const int wm = (wave & 1) << 6;
    const int wn = (wave >> 1) << 6;
    const int quad = lane >> 4;
    const int l16 = lane & 15;

    f32x4 acc[4][4];
#pragma unroll
    for (int i = 0; i < 4; i++)
#pragma unroll
        for (int j = 0; j < 4; j++) acc[i][j] = (f32x4){0.f, 0.f, 0.f, 0.f};

    const int row_s = t >> 2;   // 0..63
    const int q_s = t & 3;      // 16B chunk within 32-elem row slice

    for (int k0 = 0; k0 < 512; k0 += 32) {
        __syncthreads();
#pragma unroll
        for (int i = 0; i < 2; i++) {
            int row = row_s + (i << 6);
            int gr = m0 + row;
            u32x4 av = {0u, 0u, 0u, 0u};
            if (gr < M) av = *(const u32x4*)(A + (size_t)gr * 512 + k0 + q_s * 8);
            *(u32x4*)(&sA[row][q_s * 8]) = av;
            u32x4 bv = *(const u32x4*)(Bt + (size_t)(n0 + row) * 512 + k0 + q_s * 8);
            *(u32x4*)(&sB[row][q_s * 8]) = bv;
        }
        __syncthreads();
        bf16x8 af[4], bfr[4];
#pragma unroll
        for (int i = 0; i < 4; i++)
            af[i] = *(const bf16x8*)(&sA[wm + i * 16 + l16][quad * 8]);
#pragma unroll
        for (int j = 0; j < 4; j++)
            bfr[j] = *(const bf16x8*)(&sB[wn + j * 16 + l16][quad * 8]);
#pragma unroll
        for (int i = 0; i < 4; i++)
#pragma unroll
            for (int j = 0; j < 4; j++)
                acc[i][j] = __builtin_amdgcn_mfma_f32_16x16x32_bf16(af[i], bfr[j], acc[i][j], 0, 0, 0);
    }

    // epilogue: D row = quad*4 + r, col = l16 (verified m89/m91 mapping)
#pragma unroll
    for (int i = 0; i < 4; i++) {
        int rbase = m0 + wm + i * 16 + quad * 4;
#pragma unroll
        for (int j = 0; j < 4; j++) {
            int col = n0 + wn + j * 16 + l16;
            float bv = bias[col];
#pragma unroll
            for (int r = 0; r < 4; r++) {
                int row = rbase + r;
                if (row < M) C[(size_t)row * 512 + col] = f2bf(acc[i][j][r] + bv);
            }
        }
    }
}

// ---- SpMM + ReLU, dim-sliced, wave-per-node (4 nodes/block) ----
// lane owns dim d0+lane (2B load per edge); deg uniform per wave;
// 1-deep prefetch; non-temporal out stores.
__global__ __launch_bounds__(256)
void k_spmm(const i32x2* __restrict__ bucket, const int* __restrict__ cnt,
            const unsigned short* __restrict__ Hin,
            unsigned short* __restrict__ out_bf, float* __restrict__ out_f32) {
    __shared__ i32x2 sE[4][BUCKET_CAP];
    const int w = threadIdx.x >> 6;
    const int lane = threadIdx.x & 63;
    const int node = blockIdx.x * 4 + w;
    const int d0 = blockIdx.y * SLICE_DIM;
    int deg = cnt[node];
    if (deg > BUCKET_CAP) deg = BUCKET_CAP;
    const i32x2* bk = bucket + ((size_t)node << 7);
    if (lane < deg)      sE[w][lane]      = __builtin_nontemporal_load(bk + lane);
    if (lane + 64 < deg) sE[w][lane + 64] = __builtin_nontemporal_load(bk + lane + 64);
    __syncthreads();

    const unsigned short* __restrict__ col = Hin + d0 + lane;
    float a = 0.f;
    if (deg > 0) {
        i32x2 ed = sE[w][0];
        float v = __int_as_float(ed[1]);
        unsigned short h = col[(size_t)ed[0] << 9];
        for (int e = 1; e < deg; e++) {
            i32x2 edn = sE[w][e];
            float vn = __int_as_float(edn[1]);
            unsigned short hn = col[(size_t)edn[0] << 9];
            a += v * bf2f(h);
            h = hn; v = vn;
        }
        a += v * bf2f(h);
    }
    a = fmaxf(a, 0.f);

    const size_t o = (((size_t)node) << 9) + d0 + lane;
    if (out_f32 != nullptr) {
        __builtin_nontemporal_store(a, out_f32 + o);
    } else {
        __builtin_nontemporal_store(f2bf(a), out_bf + o);
    }
}

extern "C" void kernel_launch(void* const* d_in, const int* in_sizes, int n_in,
                              void* d_out, int out_size, void* d_ws, size_t ws_size,
                              hipStream_t stream) {
    const float* x       = (const float*)d_in[0];
    const int*   adj_src = (const int*)d_in[1];
    const int*   adj_dst = (const int*)d_in[2];
    const float* adj_val = (const float*)d_in[3];
    const float* W1      = (const float*)d_in[4];
    const float* b1      = (const float*)d_in[5];
    const float* W2      = (const float*)d_in[6];
    const float* b2      = (const float*)d_in[7];

    const size_t ND = (size_t)N_NODES * DIM;          // 51,200,000

    // workspace layout (~206 MB)
    unsigned short* xb  = (unsigned short*)d_ws;      // 102.4 MB  bf16 x / later h3
    unsigned short* w1t = xb + ND;                    // 512 KB
    unsigned short* w2t = w1t + 262144;               // 512 KB
    int*  cnt    = (int*)(w2t + 262144);              // 400 KB
    i32x2* bucket = (i32x2*)(cnt + 100096);           // 102.4 MB

    // d_out doubles as bf16 scratch (dead by the time final fp32 is written)
    unsigned short* h1 = (unsigned short*)d_out;      // 102.4 MB
    unsigned short* h2 = h1 + ND;                     // 102.4 MB
    unsigned short* h3 = xb;                          // reuse after GEMM1 consumed xb

    // 1) convert inputs to bf16
    k_cvt<<<50000, 256, 0, stream>>>((const f32x4*)x, (ushort4*)xb, (int)(ND / 4));
    k_wt<<<1024, 256, 0, stream>>>(W1, w1t);
    k_wt<<<1024, 256, 0, stream>>>(W2, w2t);

    // 2) build per-dst edge buckets (single pass)
    hipMemsetAsync(cnt, 0, N_NODES * sizeof(int), stream);
    k_scatter<<<12500, 256, 0, stream>>>(adj_src, adj_dst, adj_val, cnt, bucket);

    dim3 ggrid(4, (N_NODES + 127) / 128);
    dim3 sgrid(N_NODES / 4, NSLICE);                  // 25000 x 8

    // 3) layer 1
    k_gemm<<<ggrid, 256, 0, stream>>>(xb, w1t, b1, h1, N_NODES);
    k_spmm<<<sgrid, 256, 0, stream>>>(bucket, cnt, h1, h2, nullptr);

    // 4) layer 2
    k_gemm<<<ggrid, 256, 0, stream>>>(h2, w2t, b2, h3, N_NODES);
    k_spmm<<<sgrid, 256, 0, stream>>>(bucket, cnt, h3, nullptr, (float*)d_out);
}

// Round 7
// 1673.517 us; speedup vs baseline: 1.1661x; 1.1661x over previous
//
#include <hip/hip_runtime.h>

// GCN: h=relu(spmm(x@W1+b1)); out=relu(spmm(h@W2+b2))
// N=100000 nodes, E=3200000 edges, D=512.
// Round-0 baseline (verified pass, 1700us) with ONE edit: the gemm k-loop is
// software-pipelined (next k-tile's 4 global loads hoisted into registers
// before the MFMA block; LDS writes after the read-barrier). Everything else
// is byte-identical to the round-0 baseline.
// d_out doubles as scratch for bf16 h1/h2 (fully overwritten by final spmm).

#define N_NODES 100000
#define N_EDGES 3200000
#define DIM 512
#define BUCKET_CAP 128

typedef __attribute__((ext_vector_type(8))) __bf16 bf16x8;
typedef __attribute__((ext_vector_type(4))) float f32x4;
typedef __attribute__((ext_vector_type(4))) unsigned int u32x4;

__device__ inline unsigned short f2bf(float f) {
    unsigned int u = __builtin_bit_cast(unsigned int, f);
    unsigned int r = (u + 0x7FFFu + ((u >> 16) & 1u)) >> 16;
    return (unsigned short)r;
}
__device__ inline float bf2f(unsigned short s) {
    unsigned int u = ((unsigned int)s) << 16;
    return __builtin_bit_cast(float, u);
}

// ---- fp32 -> bf16 bulk convert (4 elems/thread) ----
__global__ __launch_bounds__(256) void k_cvt(const float4* __restrict__ in,
                                             ushort4* __restrict__ out, int n4) {
    int i = blockIdx.x * 256 + threadIdx.x;
    if (i >= n4) return;
    float4 v = in[i];
    ushort4 o;
    o.x = f2bf(v.x); o.y = f2bf(v.y); o.z = f2bf(v.z); o.w = f2bf(v.w);
    out[i] = o;
}

// ---- W [K,N] fp32 -> Wt [N,K] bf16 (512x512) ----
__global__ __launch_bounds__(256) void k_wt(const float* __restrict__ W,
                                            unsigned short* __restrict__ Wt) {
    int idx = blockIdx.x * 256 + threadIdx.x;   // 262144 total
    int k = idx & 511, n = idx >> 9;
    Wt[n * 512 + k] = f2bf(W[k * 512 + n]);
}

// ---- edge scatter into per-dst buckets (int atomics only) ----
__global__ __launch_bounds__(256) void k_scatter(const int* __restrict__ src,
                                                 const int* __restrict__ dst,
                                                 const float* __restrict__ val,
                                                 int* __restrict__ cnt,
                                                 int2* __restrict__ bucket) {
    int e = blockIdx.x * 256 + threadIdx.x;
    if (e >= N_EDGES) return;
    int d = dst[e];
    int pos = atomicAdd(cnt + d, 1);
    if (pos < BUCKET_CAP)
        bucket[((size_t)d << 7) + pos] = make_int2(src[e], __float_as_int(val[e]));
}

// ---- bf16 MFMA GEMM: C[M,512] = A[M,512] @ Bt^T + bias, C in bf16 ----
// 128x128 block tile, BK=32, 4 waves (2x2), each wave 4x4 of 16x16x32 MFMA.
// Software-pipelined: iteration k0 computes from LDS while the 4 global
// loads for k0+32 are already in flight in registers.
__global__ __launch_bounds__(256, 2)
void k_gemm(const unsigned short* __restrict__ A, const unsigned short* __restrict__ Bt,
            const float* __restrict__ bias, unsigned short* __restrict__ C, int M) {
    __shared__ unsigned short sA[128][40];   // +8 bf16 pad: 2-way-only bank aliasing
    __shared__ unsigned short sB[128][40];
    const int t = threadIdx.x;
    const int m0 = blockIdx.x * 128;
    const int n0 = blockIdx.y * 128;
    const int wave = t >> 6;
    const int lane = t & 63;
    const int wm = (wave & 1) << 6;
    const int wn = (wave >> 1) << 6;
    const int quad = lane >> 4;
    const int l16 = lane & 15;

    f32x4 acc[4][4];
#pragma unroll
    for (int i = 0; i < 4; i++)
#pragma unroll
        for (int j = 0; j < 4; j++) acc[i][j] = (f32x4){0.f, 0.f, 0.f, 0.f};

    const int row_s = t >> 2;   // 0..63; thread stages rows row_s and row_s+64
    const int q_s = t & 3;      // 16B chunk within 32-elem row slice

    const int gr0 = m0 + row_s;
    const int gr1 = m0 + row_s + 64;
    const bool ok0 = gr0 < M, ok1 = gr1 < M;
    const unsigned short* __restrict__ pA0 = A + (size_t)gr0 * 512 + q_s * 8;
    const unsigned short* __restrict__ pA1 = A + (size_t)gr1 * 512 + q_s * 8;
    const unsigned short* __restrict__ pB0 = Bt + (size_t)(n0 + row_s) * 512 + q_s * 8;
    const unsigned short* __restrict__ pB1 = Bt + (size_t)(n0 + row_s + 64) * 512 + q_s * 8;
    const u32x4 zz = (u32x4){0u, 0u, 0u, 0u};

    // prologue: k-tile 0 -> regs -> LDS
    u32x4 a0r = ok0 ? *(const u32x4*)(pA0) : zz;
    u32x4 a1r = ok1 ? *(const u32x4*)(pA1) : zz;
    u32x4 b0r = *(const u32x4*)(pB0);
    u32x4 b1r = *(const u32x4*)(pB1);
    *(u32x4*)(&sA[row_s][q_s * 8]) = a0r;
    *(u32x4*)(&sA[row_s + 64][q_s * 8]) = a1r;
    *(u32x4*)(&sB[row_s][q_s * 8]) = b0r;
    *(u32x4*)(&sB[row_s + 64][q_s * 8]) = b1r;
    __syncthreads();

    for (int k0 = 0; k0 < 512; k0 += 32) {
        const bool more = (k0 + 32) < 512;
        if (more) {
            a0r = ok0 ? *(const u32x4*)(pA0 + k0 + 32) : zz;
            a1r = ok1 ? *(const u32x4*)(pA1 + k0 + 32) : zz;
            b0r = *(const u32x4*)(pB0 + k0 + 32);
            b1r = *(const u32x4*)(pB1 + k0 + 32);
        }
        bf16x8 af[4], bfr[4];
#pragma unroll
        for (int i = 0; i < 4; i++)
            af[i] = *(const bf16x8*)(&sA[wm + i * 16 + l16][quad * 8]);
#pragma unroll
        for (int j = 0; j < 4; j++)
            bfr[j] = *(const bf16x8*)(&sB[wn + j * 16 + l16][quad * 8]);
#pragma unroll
        for (int i = 0; i < 4; i++)
#pragma unroll
            for (int j = 0; j < 4; j++)
                acc[i][j] = __builtin_amdgcn_mfma_f32_16x16x32_bf16(af[i], bfr[j], acc[i][j], 0, 0, 0);
        if (more) {
            __syncthreads();   // all waves done reading this k-tile
            *(u32x4*)(&sA[row_s][q_s * 8]) = a0r;
            *(u32x4*)(&sA[row_s + 64][q_s * 8]) = a1r;
            *(u32x4*)(&sB[row_s][q_s * 8]) = b0r;
            *(u32x4*)(&sB[row_s + 64][q_s * 8]) = b1r;
            __syncthreads();   // next k-tile visible
        }
    }

    // epilogue: D row = quad*4 + r, col = l16 (verified m89/m91 mapping)
#pragma unroll
    for (int i = 0; i < 4; i++) {
        int rbase = m0 + wm + i * 16 + quad * 4;
#pragma unroll
        for (int j = 0; j < 4; j++) {
            int col = n0 + wn + j * 16 + l16;
            float bv = bias[col];
#pragma unroll
            for (int r = 0; r < 4; r++) {
                int row = rbase + r;
                if (row < M) C[(size_t)row * 512 + col] = f2bf(acc[i][j][r] + bv);
            }
        }
    }
}

// ---- SpMM + ReLU: one block per dst node; 256 thr x 2 dims ----
// out[dst][d] = relu( sum_e val_e * Hin[src_e][d] )
__global__ __launch_bounds__(256)
void k_spmm(const int2* __restrict__ bucket, const int* __restrict__ cnt,
            const unsigned short* __restrict__ Hin,
            unsigned short* __restrict__ out_bf, float* __restrict__ out_f32) {
    __shared__ int2 sE[BUCKET_CAP];
    int node = blockIdx.x;
    int t = threadIdx.x;
    int deg = cnt[node];
    if (deg > BUCKET_CAP) deg = BUCKET_CAP;
    if (t < deg) sE[t] = bucket[((size_t)node << 7) + t];
    __syncthreads();
    float ax = 0.f, ay = 0.f;
    for (int e = 0; e < deg; e++) {
        int2 ed = sE[e];
        float v = __int_as_float(ed.y);
        unsigned int p = *(const unsigned int*)(Hin + ((size_t)ed.x << 9) + (t << 1));
        ax += v * bf2f((unsigned short)(p & 0xFFFFu));
        ay += v * bf2f((unsigned short)(p >> 16));
    }
    ax = fmaxf(ax, 0.f);
    ay = fmaxf(ay, 0.f);
    size_t o = ((size_t)node << 9) + (t << 1);
    if (out_f32 != nullptr) {
        float2 st = make_float2(ax, ay);
        *(float2*)(out_f32 + o) = st;
    } else {
        unsigned int pk = (unsigned int)f2bf(ax) | ((unsigned int)f2bf(ay) << 16);
        *(unsigned int*)(out_bf + o) = pk;
    }
}

extern "C" void kernel_launch(void* const* d_in, const int* in_sizes, int n_in,
                              void* d_out, int out_size, void* d_ws, size_t ws_size,
                              hipStream_t stream) {
    const float* x       = (const float*)d_in[0];
    const int*   adj_src = (const int*)d_in[1];
    const int*   adj_dst = (const int*)d_in[2];
    const float* adj_val = (const float*)d_in[3];
    const float* W1      = (const float*)d_in[4];
    const float* b1      = (const float*)d_in[5];
    const float* W2      = (const float*)d_in[6];
    const float* b2      = (const float*)d_in[7];

    const size_t ND = (size_t)N_NODES * DIM;          // 51,200,000

    // workspace layout (~206 MB)
    unsigned short* xb  = (unsigned short*)d_ws;      // 102.4 MB  bf16 x / later h3
    unsigned short* w1t = xb + ND;                    // 512 KB
    unsigned short* w2t = w1t + 262144;               // 512 KB
    int*  cnt    = (int*)(w2t + 262144);              // 400 KB
    int2* bucket = (int2*)(cnt + 100096);             // 102.4 MB

    // d_out doubles as bf16 scratch (dead by the time final fp32 is written)
    unsigned short* h1 = (unsigned short*)d_out;      // 102.4 MB
    unsigned short* h2 = h1 + ND;                     // 102.4 MB
    unsigned short* h3 = xb;                          // reuse after GEMM1 consumed xb

    // 1) convert inputs to bf16
    k_cvt<<<50000, 256, 0, stream>>>((const float4*)x, (ushort4*)xb, (int)(ND / 4));
    k_wt<<<1024, 256, 0, stream>>>(W1, w1t);
    k_wt<<<1024, 256, 0, stream>>>(W2, w2t);

    // 2) build per-dst edge buckets
    hipMemsetAsync(cnt, 0, N_NODES * sizeof(int), stream);
    k_scatter<<<12500, 256, 0, stream>>>(adj_src, adj_dst, adj_val, cnt, bucket);

    dim3 ggrid((N_NODES + 127) / 128, 4);

    // 3) layer 1
    k_gemm<<<ggrid, 256, 0, stream>>>(xb, w1t, b1, h1, N_NODES);
    k_spmm<<<N_NODES, 256, 0, stream>>>(bucket, cnt, h1, h2, nullptr);

    // 4) layer 2
    k_gemm<<<ggrid, 256, 0, stream>>>(h2, w2t, b2, h3, N_NODES);
    k_spmm<<<N_NODES, 256, 0, stream>>>(bucket, cnt, h3, nullptr, (float*)d_out);
}